// Round 10
// baseline (52.668 us; speedup 1.0000x reference)
//
#include <hip/hip_runtime.h>

#define NBATCH 4096
#define NT 2048
#define NP 1024
#define KT 4              // conv half-width
#define NTH 256           // reduce-kernel block size

// odd-stride LDS padding: lane-stride 16 -> 17 dwords (conflict-free)
__device__ __forceinline__ int pp(int x) { return x + (x >> 4); }

__global__ __launch_bounds__(64, 4) void w2loss_kernel(
    const float* __restrict__ f,
    const float* __restrict__ obs,
    float* __restrict__ partial)
{
    __shared__ float sQp[1087];   // padded q
    __shared__ float sMp[1087];   // padded M

    const int lane = threadIdx.x;          // 0..63 (one wave per block/row)
    const int b    = blockIdx.x;

    const float dt      = 0.001f;
    const float half_dt = 0.0005f;
    const float h       = 0.00097751710654936461f;  // 1/1023
    const float inv_h   = 1023.0f;
    const float inv_h2  = 1046529.0f;
    const float h6      = h * (1.0f / 6.0f);
    const float ih6     = inv_h * (1.0f / 6.0f);

    const float* orow = obs + (size_t)b * NT;
    const float* frow = f   + (size_t)b * NT;

    // issue ALL global loads up front; f's latency hides under phase A
    float4 ov[8], fv[8];
#pragma unroll
    for (int c = 0; c < 4; ++c) {
        const int base = c * 512 + lane * 8;
        ov[2*c]   = *reinterpret_cast<const float4*>(orow + base);
        ov[2*c+1] = *reinterpret_cast<const float4*>(orow + base + 4);
        fv[2*c]   = *reinterpret_cast<const float4*>(frow + base);
        fv[2*c+1] = *reinterpret_cast<const float4*>(frow + base + 4);
    }

    // ---------------- A1: obs squares + chunked wave scans ----------------
    float sq[32];
    float excl[4], W6[4], W7[4], carry[4];
    float run = 0.0f;
#pragma unroll
    for (int c = 0; c < 4; ++c) {
        float4 a = ov[2*c], bb = ov[2*c+1];
        sq[c*8+0]=a.x*a.x;  sq[c*8+1]=a.y*a.y;  sq[c*8+2]=a.z*a.z;  sq[c*8+3]=a.w*a.w;
        sq[c*8+4]=bb.x*bb.x; sq[c*8+5]=bb.y*bb.y; sq[c*8+6]=bb.z*bb.z; sq[c*8+7]=bb.w*bb.w;
        float p[8];
        p[0] = sq[c*8];
#pragma unroll
        for (int e = 1; e < 8; ++e) p[e] = p[e-1] + sq[c*8+e];
        float tsum = p[7];
        float ws = tsum;
#pragma unroll
        for (int off = 1; off < 64; off <<= 1) {
            float u = __shfl_up(ws, off);
            if (lane >= off) ws += u;
        }
        float ex = ws - tsum;
        excl[c] = ex;
        float w6 = ex + p[6];
        float w7 = ex + p[7];
        W6[c] = __shfl(w6, 63);
        W7[c] = __shfl(w7, 63);
        carry[c] = run;            // prefix total BEFORE this chunk
        run = run + W7[c];
    }
    const float totA = run;
    const float sq0A = __shfl(sq[0], 0);
    const float sqLA = __shfl(sq[31], 63);
    const float invSA = 1.0f / (half_dt * (2.0f * totA - sqLA - sq0A));

    // ---------------- A2: inverse-CDF forward scatter (exact partition) ----------------
#pragma unroll
    for (int c = 0; c < 4; ++c) {
        float p[8];
        p[0] = sq[c*8];
#pragma unroll
        for (int e = 1; e < 8; ++e) p[e] = p[e-1] + sq[c*8+e];
        float w6 = excl[c] + p[6];
        float w7 = excl[c] + p[7];
        float sw6 = __shfl_up(w6, 1);
        float sw7 = __shfl_up(w7, 1);

        float cm, Pm;
        if (lane == 0) {
            if (c == 0) { cm = -1.0f; Pm = 0.0f; }
            else {
                cm = half_dt * (((carry[c-1] + W6[c-1]) + (carry[c-1] + W7[c-1])) - sq0A) * invSA;
                Pm = carry[c];
            }
        } else {
            cm = half_dt * (((carry[c] + sw6) + (carry[c] + sw7)) - sq0A) * invSA;
            Pm = carry[c] + sw7;
        }

#pragma unroll
        for (int e = 0; e < 8; ++e) {
            const int j = c * 512 + lane * 8 + e;
            float Pj = carry[c] + (excl[c] + p[e]);
            float cc = (j == 0) ? 0.0f : half_dt * ((Pm + Pj) - sq0A) * invSA;
            int kLo = (int)floorf(cm * inv_h) + 1;
            if (kLo < 0) kLo = 0;
            int kHi;
            if (j == NT - 1) kHi = NP - 1;
            else { kHi = (int)floorf(cc * inv_h); if (kHi > NP - 1) kHi = NP - 1; }
            const float qvj = (float)j * dt;
            for (int k = kLo; k <= kHi; ++k) sQp[pp(k)] = qvj;
            cm = cc; Pm = Pj;
        }
    }

    // ---------------- B1: f squares + chunked scans (overlaps scatter latency) ----------------
    float exB[4], W7B[4], carryB[4];
    float runB = 0.0f;
#pragma unroll
    for (int c = 0; c < 4; ++c) {
        float4 a = fv[2*c], bb = fv[2*c+1];
        sq[c*8+0]=a.x*a.x;  sq[c*8+1]=a.y*a.y;  sq[c*8+2]=a.z*a.z;  sq[c*8+3]=a.w*a.w;
        sq[c*8+4]=bb.x*bb.x; sq[c*8+5]=bb.y*bb.y; sq[c*8+6]=bb.z*bb.z; sq[c*8+7]=bb.w*bb.w;
        float p[8];
        p[0] = sq[c*8];
#pragma unroll
        for (int e = 1; e < 8; ++e) p[e] = p[e-1] + sq[c*8+e];
        float tsum = p[7];
        float ws = tsum;
#pragma unroll
        for (int off = 1; off < 64; off <<= 1) {
            float u = __shfl_up(ws, off);
            if (lane >= off) ws += u;
        }
        float ex = ws - tsum;
        exB[c] = ex;
        W7B[c] = __shfl(ex + p[7], 63);
        carryB[c] = runB;
        runB = runB + W7B[c];
    }
    const float totB = runB;
    const float sq0B = __shfl(sq[0], 0);
    const float sqLB = __shfl(sq[31], 63);
    const float invSB = 1.0f / (half_dt * (2.0f * totB - sqLB - sq0B));

    __syncthreads();   // single-wave barrier (~free): scatter visible to stencil reads

    // ---------------- stencil: q -> rhs (regs) -> M, images on edge lanes ----------------
    {
        const float Cg = 0.28867513459481288f; // 1/(2*sqrt(3))
        const float CP[KT + 1] = {
            1.0f, -0.26794919243112270f, 0.071796769724490830f,
            -0.019237886466840586f, 0.0051547761428899979f };
        const float RPW[14] = {
            1.0f, -0.26794919243112270f, 0.071796769724490830f,
            -0.019237886466840586f, 0.0051547761428899979f,
            -0.0013812184239975285f, 0.00037009627398250260f,
            -9.9166998940445055e-05f, 2.6571322000000000e-05f,
            -7.1197520000000000e-06f, 1.9076502000000000e-06f,
            -5.1115295000000000e-07f, 1.3696300000000000e-07f,
            -3.6699170000000000e-08f };

        const int k0 = lane * 16;
        float r[24];     // rhs_{k0-5+x}, x in [0,23]; rhs_i valid for i in [0,1021]
        {
            int i0 = k0 - 5;
            float q0r = sQp[pp(i0 < 0 ? 0 : i0)];
            float q1r = sQp[pp(i0 + 1 < 0 ? 0 : i0 + 1)];
#pragma unroll
            for (int x = 0; x < 24; ++x) {
                int gi = i0 + x;
                int qi = gi + 2;
                float q2r = sQp[pp(qi > 1023 ? 1023 : (qi < 0 ? 0 : qi))];
                float v = 6.0f * (q0r - 2.0f * q1r + q2r) * inv_h2;
                r[x] = (gi >= 0 && gi <= 1021) ? v : 0.0f;
                q0r = q1r; q1r = q2r;
            }
        }

        float acc[16];
#pragma unroll
        for (int m = 0; m < 16; ++m) {
            float a = CP[0] * r[m + 4];
#pragma unroll
            for (int d = 1; d <= KT; ++d) a += CP[d] * (r[m + 4 - d] + r[m + 4 + d]);
            acc[m] = a;
        }
        if (lane == 0) {
            float T1 = 0.0f;
#pragma unroll
            for (int k2 = 0; k2 < 13; ++k2) T1 += RPW[k2 + 1] * r[5 + k2];
#pragma unroll
            for (int m = 1; m < 14; ++m) acc[m] -= RPW[m] * T1;
        } else if (lane == 63) {
            float T2 = 0.0f;
#pragma unroll
            for (int k2 = 0; k2 < 13; ++k2) T2 += RPW[13 - k2] * r[6 + k2];
#pragma unroll
            for (int m = 2; m < 15; ++m) acc[m] -= RPW[15 - m] * T2;
        }
#pragma unroll
        for (int m = 0; m < 16; ++m) {
            const int k = k0 + m;
            float mv = Cg * acc[m];
            if (k == 0 || k == NP - 1) mv = 0.0f;
            sMp[pp(k)] = mv;
        }
    }

    __syncthreads();   // single-wave barrier (~free): M visible to phase-B gathers

    // ---------------- B2: F in registers, padded gathers, integrate ----------------
    float local = 0.0f, term0 = 0.0f, term7 = 0.0f;
    const float c1B = half_dt * invSB;
#pragma unroll
    for (int c = 0; c < 4; ++c) {
        float p[8];
        p[0] = sq[c*8];
#pragma unroll
        for (int e = 1; e < 8; ++e) p[e] = p[e-1] + sq[c*8+e];
        const float bcc = carryB[c] + exB[c];
#pragma unroll
        for (int e = 0; e < 8; ++e) {
            const int j = c * 512 + lane * 8 + e;
            float sqe = sq[c*8+e];
            float P = bcc + p[e];
            float F = (((P - sqe) + P) - sq0B) * c1B;      // exact 0 at j==0
            float kf = F * inv_h;
            kf = fminf(fmaxf(kf, 0.0f), 1022.0f);
            int k = (int)kf;
            float s = __builtin_fmaf(-h, (float)k, F);
            float q0 = sQp[pp(k)];
            float q1 = sQp[pp(k + 1)];
            float M0 = sMp[pp(k)];
            float M1 = sMp[pp(k + 1)];
            float bco = (q1 - q0) * inv_h - (2.0f * M0 + M1) * h6;
            float od  = q0 + s * (bco + s * (0.5f * M0 + s * (M1 - M0) * ih6));
            float tj  = (float)j * dt;
            float dd  = tj - od;
            float term = dd * dd * sqe;
            local += term;
            if (c == 0 && e == 0) term0 = term;
            if (c == 3 && e == 7) term7 = term;
        }
    }
    if (lane == 0)  local -= 0.5f * term0;   // trapezoid half-weight at j=0
    if (lane == 63) local -= 0.5f * term7;   // and at j=NT-1

#pragma unroll
    for (int off = 32; off > 0; off >>= 1) local += __shfl_down(local, off);
    if (lane == 0) partial[b] = local * (dt * invSB);
}

// fixed-order deterministic reduction of 4096 partials -> scalar
__global__ __launch_bounds__(NTH) void w2loss_reduce(
    const float* __restrict__ partial, float* __restrict__ out)
{
    __shared__ float sRed[4];
    const int tid  = threadIdx.x;
    const int lane = tid & 63;
    const int wid  = tid >> 6;
    float s = 0.0f;
#pragma unroll
    for (int i = 0; i < 16; i += 4) {
        float4 v = *reinterpret_cast<const float4*>(partial + tid * 16 + i);
        s += v.x + v.y + v.z + v.w;
    }
#pragma unroll
    for (int off = 32; off > 0; off >>= 1) s += __shfl_down(s, off);
    if (lane == 0) sRed[wid] = s;
    __syncthreads();
    if (tid == 0) out[0] = sRed[0] + sRed[1] + sRed[2] + sRed[3];
}

extern "C" void kernel_launch(void* const* d_in, const int* in_sizes, int n_in,
                              void* d_out, int out_size, void* d_ws, size_t ws_size,
                              hipStream_t stream) {
    const float* f   = (const float*)d_in[0];
    const float* obs = (const float*)d_in[1];
    float* out     = (float*)d_out;
    float* partial = (float*)d_ws;   // 4096 floats = 16 KB scratch

    w2loss_kernel<<<NBATCH, 64, 0, stream>>>(f, obs, partial);
    w2loss_reduce<<<1, NTH, 0, stream>>>(partial, out);
}

// Round 11
// 30.712 us; speedup vs baseline: 1.7149x; 1.7149x over previous
//
#include <hip/hip_runtime.h>

#define NBATCH 4096
#define NT 2048
#define NP 1024
#define NTH 256
#define EPT 8   // NT elements per thread
#define PPT 4   // NP items per thread
#define MSZ 1022          // interior system size (NP-2)
#define KT 4              // conv half-width: |rho|^5 ~ 1.4e-3 rel on M -> ~7e-6 on od
#define IMGW 14           // boundary image reach

// stride-9 LDS padding: breaks power-of-2 patterns; residual aliasing <=2-way (free)
__device__ __forceinline__ int pI(int x) { return x + (x >> 3); }   // x in [0,1025] -> max 1153

__global__ __launch_bounds__(NTH, 8) void w2loss_kernel(
    const float* __restrict__ f,
    const float* __restrict__ obs,
    float* __restrict__ partial)
{
    __shared__ float sQp[1156];          // padded q
    __shared__ float sMp[1156];          // padded M
    __shared__ float sRp[MSZ + 2 * KT];  // zero-padded rhs (linear)
    __shared__ float sH[NTH];            // prev-thread last square handoff
    __shared__ float sPow[IMGW];         // rho^d
    __shared__ float sWSA[4], sWSB[4];
    __shared__ float sSqA[2], sSqB[2];
    __shared__ float sRed[4];

    const int tid  = threadIdx.x;
    const int lane = tid & 63;
    const int wid  = tid >> 6;
    const int b    = blockIdx.x;
    const int base = tid * EPT;

    const float dt      = 0.001f;
    const float half_dt = 0.0005f;
    const float h       = 0.00097751710654936461f;  // 1/1023
    const float inv_h   = 1023.0f;
    const float inv_h2  = 1046529.0f;               // 1023^2
    const float h6      = h * (1.0f / 6.0f);
    const float ih6     = inv_h * (1.0f / 6.0f);

    const float* orow = obs + (size_t)b * NT;
    const float* frow = f   + (size_t)b * NT;
    float4 o0 = *reinterpret_cast<const float4*>(orow + base);
    float4 o1 = *reinterpret_cast<const float4*>(orow + base + 4);
    float4 g0 = *reinterpret_cast<const float4*>(frow + base);
    float4 g1 = *reinterpret_cast<const float4*>(frow + base + 4);

    if (tid < IMGW) {
        const float rho = -0.26794919243112270f;
        float v = 1.0f;
        for (int i = 0; i < tid; ++i) v *= rho;
        sPow[tid] = v;
    }
    if (tid < KT) { sRp[tid] = 0.0f; sRp[KT + MSZ + tid] = 0.0f; }

    // ---- squares + per-thread prefixes for BOTH rows ----
    float prefA[EPT], prefB[EPT];
    {
        float s0;
        s0 = o0.x*o0.x; prefA[0] = s0;
        s0 = o0.y*o0.y; prefA[1] = prefA[0] + s0;
        s0 = o0.z*o0.z; prefA[2] = prefA[1] + s0;
        s0 = o0.w*o0.w; prefA[3] = prefA[2] + s0;
        s0 = o1.x*o1.x; prefA[4] = prefA[3] + s0;
        s0 = o1.y*o1.y; prefA[5] = prefA[4] + s0;
        s0 = o1.z*o1.z; prefA[6] = prefA[5] + s0;
        s0 = o1.w*o1.w; prefA[7] = prefA[6] + s0;
        s0 = g0.x*g0.x; prefB[0] = s0;
        s0 = g0.y*g0.y; prefB[1] = prefB[0] + s0;
        s0 = g0.z*g0.z; prefB[2] = prefB[1] + s0;
        s0 = g0.w*g0.w; prefB[3] = prefB[2] + s0;
        s0 = g1.x*g1.x; prefB[4] = prefB[3] + s0;
        s0 = g1.y*g1.y; prefB[5] = prefB[4] + s0;
        s0 = g1.z*g1.z; prefB[6] = prefB[5] + s0;
        s0 = g1.w*g1.w; prefB[7] = prefB[6] + s0;
    }
    float sqA7 = o1.w * o1.w;
    float sqB7 = g1.w * g1.w;
    sH[tid] = sqA7;                      // handoff BEFORE B1 (read after B1)

    // ---- interleaved wave scans (2x ILP) ----
    float tsA = prefA[EPT - 1], tsB = prefB[EPT - 1];
    float wsA = tsA, wsB = tsB;
#pragma unroll
    for (int off = 1; off < 64; off <<= 1) {
        float uA = __shfl_up(wsA, off);
        float uB = __shfl_up(wsB, off);
        if (lane >= off) { wsA += uA; wsB += uB; }
    }
    if (lane == 63) { sWSA[wid] = wsA; sWSB[wid] = wsB; }
    if (tid == 0)       { sSqA[0] = prefA[0]; sSqB[0] = prefB[0]; }
    if (tid == NTH - 1) { sSqA[1] = sqA7;     sSqB[1] = sqB7; }
    __syncthreads();                                            // B1

    float exclA = wsA - tsA, exclB = wsB - tsB;
    if (wid > 0) { exclA += sWSA[0]; exclB += sWSB[0]; }
    if (wid > 1) { exclA += sWSA[1]; exclB += sWSB[1]; }
    if (wid > 2) { exclA += sWSA[2]; exclB += sWSB[2]; }
    float totA = sWSA[0] + sWSA[1] + sWSA[2] + sWSA[3];
    float totB = sWSB[0] + sWSB[1] + sWSB[2] + sWSB[3];
    float sq0A = sSqA[0], sq0B = sSqB[0];
    float invSA = 1.0f / (half_dt * (2.0f * totA - sSqA[1] - sq0A));
    float invSB = 1.0f / (half_dt * (2.0f * totB - sSqB[1] - sq0B));

    // ---- inverse-CDF by forward scatter: j claims p_k in (c_{j-1}, c_j] ----
    {
        float cm;
        if (tid == 0) cm = -1.0f;
        else {
            float sqprev = sH[tid - 1];
            cm = half_dt * (((exclA - sqprev) + exclA) - sq0A) * invSA;
        }
        float Pm = exclA;
#pragma unroll
        for (int e = 0; e < EPT; ++e) {
            int j = base + e;
            float Pj = exclA + prefA[e];
            float cc = (j == 0) ? 0.0f : half_dt * (Pm + Pj - sq0A) * invSA;
            int kLo = (int)floorf(cm * inv_h) + 1;
            int kHi = (int)floorf(cc * inv_h);
            if (kLo < 0) kLo = 0;
            if (j == NT - 1) kHi = NP - 1;          // guarantee k=1023 coverage
            else {
                if (e == EPT - 1) kHi += 1;         // bridge thread-boundary ulp gap
                if (kHi > NP - 1) kHi = NP - 1;
            }
            float qv = (float)j * dt;
            for (int k = kLo; k <= kHi; ++k) sQp[pI(k)] = qv;
            cm = cc;
            Pm = Pj;
        }
    }
    __syncthreads();                                            // B2

    // ---- rhs (strided, padded reads, linear writes) ----
#pragma unroll
    for (int kk = 0; kk < PPT; ++kk) {
        int i = tid + kk * NTH;
        if (i < MSZ)
            sRp[KT + i] = 6.0f * (sQp[pI(i)] - 2.0f * sQp[pI(i + 1)] + sQp[pI(i + 2)]) * inv_h2;
    }
    __syncthreads();                                            // B3

    // ---- tridiagonal solve: constant-tap conv + redundant boundary images ----
    {
        const float Cg = 0.28867513459481288f; // 1/(2*sqrt(3))
        const float CP[KT + 1] = {
            1.0f, -0.26794919243112270f, 0.071796769724490830f,
            -0.019237886466840586f, 0.0051547761428899979f };
#pragma unroll
        for (int kk = 0; kk < PPT; ++kk) {
            int i = tid + kk * NTH;
            if (i < MSZ) {
                float acc = 0.0f;
#pragma unroll
                for (int d = -KT; d <= KT; ++d) {
                    int ad = d < 0 ? -d : d;
                    acc += CP[ad] * sRp[KT + i + d];
                }
                if (i + 1 < IMGW) {
                    float t1 = 0.0f;
#pragma unroll
                    for (int k2 = 0; k2 < IMGW - 1; ++k2) t1 += sPow[k2 + 1] * sRp[KT + k2];
                    acc -= sPow[i + 1] * t1;
                }
                if (MSZ - i < IMGW) {
                    float t2 = 0.0f;
#pragma unroll
                    for (int k2 = MSZ - IMGW + 1; k2 < MSZ; ++k2) t2 += sPow[MSZ - k2] * sRp[KT + k2];
                    acc -= sPow[MSZ - i] * t2;
                }
                sMp[pI(i + 1)] = Cg * acc;
            }
        }
    }
    if (tid == 0) { sMp[pI(0)] = 0.0f; sMp[pI(NP - 1)] = 0.0f; }
    __syncthreads();                                            // B4

    // ---- Phase B: F in registers, padded b32 gathers, inline coeffs, integrate ----
    float local = 0.0f;
    float term0 = 0.0f, term7 = 0.0f;
    {
        const float c1B = half_dt * invSB;
        const float K0  = (2.0f * exclB - sq0B) * c1B;
        float tj = (float)base * dt;
#pragma unroll
        for (int e = 0; e < EPT; ++e) {
            float Gj = (e ? prefB[e - 1] : 0.0f) + prefB[e];
            float Fj = __builtin_fmaf(Gj, c1B, K0);   // ~exact 0 at j==0
            float sqe = e ? (prefB[e] - prefB[e - 1]) : prefB[0];
            float kf = Fj * inv_h;
            kf = fminf(fmaxf(kf, 0.0f), 1022.0f);
            int k = (int)kf;
            float s = __builtin_fmaf(-h, (float)k, Fj);
            float q0 = sQp[pI(k)];
            float q1 = sQp[pI(k + 1)];
            float M0 = sMp[pI(k)];
            float M1 = sMp[pI(k + 1)];
            float bco = (q1 - q0) * inv_h - (2.0f * M0 + M1) * h6;
            float od  = q0 + s * (bco + s * (0.5f * M0 + s * (M1 - M0) * ih6));
            float dd  = tj - od;
            float term = dd * dd * sqe;
            local += term;
            if (e == 0) term0 = term;
            if (e == EPT - 1) term7 = term;
            tj += dt;
        }
    }
    if (tid == 0)       local -= 0.5f * term0;   // trapezoid half-weight at j=0
    if (tid == NTH - 1) local -= 0.5f * term7;   // and at j=NT-1

#pragma unroll
    for (int off = 32; off > 0; off >>= 1) local += __shfl_down(local, off);
    if (lane == 0) sRed[wid] = local;
    __syncthreads();                                            // B5
    if (tid == 0) partial[b] = (sRed[0] + sRed[1] + sRed[2] + sRed[3]) * (dt * invSB);
}

// fixed-order deterministic reduction of 4096 partials -> scalar
__global__ __launch_bounds__(NTH) void w2loss_reduce(
    const float* __restrict__ partial, float* __restrict__ out)
{
    __shared__ float sRed[4];
    const int tid  = threadIdx.x;
    const int lane = tid & 63;
    const int wid  = tid >> 6;
    float s = 0.0f;
#pragma unroll
    for (int i = 0; i < 16; i += 4) {
        float4 v = *reinterpret_cast<const float4*>(partial + tid * 16 + i);
        s += v.x + v.y + v.z + v.w;
    }
#pragma unroll
    for (int off = 32; off > 0; off >>= 1) s += __shfl_down(s, off);
    if (lane == 0) sRed[wid] = s;
    __syncthreads();
    if (tid == 0) out[0] = sRed[0] + sRed[1] + sRed[2] + sRed[3];
}

extern "C" void kernel_launch(void* const* d_in, const int* in_sizes, int n_in,
                              void* d_out, int out_size, void* d_ws, size_t ws_size,
                              hipStream_t stream) {
    const float* f   = (const float*)d_in[0];
    const float* obs = (const float*)d_in[1];
    float* out     = (float*)d_out;
    float* partial = (float*)d_ws;   // 4096 floats = 16 KB scratch

    w2loss_kernel<<<NBATCH, NTH, 0, stream>>>(f, obs, partial);
    w2loss_reduce<<<1, NTH, 0, stream>>>(partial, out);
}